// Round 17
// baseline (175.323 us; speedup 1.0000x reference)
//
#include <hip/hip_runtime.h>

#define B_   2
#define C_   256
#define N_   4096
#define H_   8
#define HD_  32
#define G_   8
#define CPG_ 32

typedef short short8 __attribute__((ext_vector_type(8)));
typedef float f32x4  __attribute__((ext_vector_type(4)));
typedef float f4     __attribute__((ext_vector_type(4)));

__device__ __forceinline__ float b2f(short s) {
    return __uint_as_float(((unsigned)(unsigned short)s) << 16);
}
__device__ __forceinline__ short f2b(float f) {
    unsigned u = __float_as_uint(f);
    unsigned r = (u + 0x7FFF + ((u >> 16) & 1)) >> 16;  // RNE
    return (short)r;
}

// ---------------- Node 1: GN partial sums (1024 blocks) ----------------
__global__ __launch_bounds__(256) void gn_part(const float* __restrict__ x,
                                               float* __restrict__ part) {
    int blk = blockIdx.x;
    const f4* p = (const f4*)x + (size_t)(blk >> 6) * (CPG_ * N_ / 4) + (size_t)(blk & 63) * 512;
    float s = 0.f, ss = 0.f;
#pragma unroll
    for (int i = 0; i < 2; i++) {
        f4 v = p[threadIdx.x + i * 256];
#pragma unroll
        for (int j = 0; j < 4; j++) { float f = v[j]; s += f; ss += f * f; }
    }
#pragma unroll
    for (int off = 32; off > 0; off >>= 1) {
        s  += __shfl_down(s, off);
        ss += __shfl_down(ss, off);
    }
    __shared__ float rs[4], rss[4];
    int w = threadIdx.x >> 6;
    if ((threadIdx.x & 63) == 0) { rs[w] = s; rss[w] = ss; }
    __syncthreads();
    if (threadIdx.x == 0) {
        part[blk * 2]     = rs[0] + rs[1] + rs[2] + rs[3];
        part[blk * 2 + 1] = rss[0] + rss[1] + rss[2] + rss[3];
    }
}

// ---------------- Node 2: fused GN-apply + QKV GEMM (768 blocks, 3/CU) ----------------
__global__ __launch_bounds__(256) void gemm_qkv(
    const float* __restrict__ x,
    const float* __restrict__ gw, const float* __restrict__ gb,
    const float* __restrict__ part,
    const float* __restrict__ wq, const float* __restrict__ bq,
    const float* __restrict__ wk, const float* __restrict__ bk,
    const float* __restrict__ wv, const float* __restrict__ bv,
    short* __restrict__ q, short* __restrict__ kt, short* __restrict__ v) {
    int z = blockIdx.z;
    int b = z / 3, which = z % 3;
    const float* W    = which == 0 ? wq : (which == 1 ? wk : wv);
    const float* bias = which == 0 ? bq : (which == 1 ? bk : bv);
    bool trans = (which != 2);
    float mul = (which == 0) ? (0.17677669529663687f * 1.4426950408889634f) : 1.0f;

    __shared__ short wl[64][40];
    __shared__ short xl[128][40];
    __shared__ float ga[256], gbb[256];
    __shared__ float mus[8], rstds[8];

    int o0 = blockIdx.y * 64, n0 = blockIdx.x * 128;
    int tid = threadIdx.x;
    int w = tid >> 6, lane = tid & 63, li = lane & 15, quad = lane >> 4;
    int wr = w & 1, wc = w >> 1;

#pragma unroll
    for (int gi = 0; gi < 2; gi++) {
        int g = w * 2 + gi;
        const float* pp = &part[(size_t)(b * 8 + g) * 128 + lane * 2];
        float s = pp[0], ss = pp[1];
#pragma unroll
        for (int off = 32; off > 0; off >>= 1) {
            s  += __shfl_down(s, off);
            ss += __shfl_down(ss, off);
        }
        if (lane == 0) {
            const float inv = 1.f / (float)(CPG_ * N_);
            float mu = s * inv;
            float var = ss * inv - mu * mu;
            mus[g] = mu;
            rstds[g] = rsqrtf(var + 1e-5f);
        }
    }
    __syncthreads();
    {
        int c = tid, g = c >> 5;
        float a = rstds[g] * gw[c];
        ga[c]  = a;
        gbb[c] = gb[c] - mus[g] * a;
    }

    f32x4 acc[8];
#pragma unroll
    for (int i = 0; i < 8; i++) acc[i] = (f32x4){0.f, 0.f, 0.f, 0.f};

    int cpair = tid >> 4, l16 = tid & 15;
    __syncthreads();

    for (int k0 = 0; k0 < 256; k0 += 32) {
        {
            int row = tid >> 2, co = (tid & 3) << 3;
            const float* wp = &W[(size_t)(o0 + row) * 256 + k0 + co];
            f4 wa = *(const f4*)wp;
            f4 wb = *(const f4*)(wp + 4);
            short8 w8;
#pragma unroll
            for (int j = 0; j < 4; j++) { w8[j] = f2b(wa[j]); w8[j + 4] = f2b(wb[j]); }
            *(short8*)&wl[row][co] = w8;
        }
        {
            int c0 = k0 + cpair * 2;
            float a0 = ga[c0],     b0c = gbb[c0];
            float a1 = ga[c0 + 1], b1c = gbb[c0 + 1];
            const float* xr0 = x + ((size_t)(b * 256 + c0)) * N_ + n0 + l16;
            const float* xr1 = xr0 + N_;
#pragma unroll
            for (int j = 0; j < 8; j++) {
                unsigned lo = (unsigned short)f2b(xr0[16 * j] * a0 + b0c);
                unsigned hi = (unsigned short)f2b(xr1[16 * j] * a1 + b1c);
                *(unsigned*)&xl[l16 + 16 * j][cpair * 2] = lo | (hi << 16);
            }
        }
        __syncthreads();
        short8 af[4], bfr[4];
        if (trans) {
#pragma unroll
            for (int i = 0; i < 4; i++) af[i]  = *(short8*)&xl[wr * 64 + i * 16 + li][quad * 8];
#pragma unroll
            for (int j = 0; j < 2; j++) bfr[j] = *(short8*)&wl[wc * 32 + j * 16 + li][quad * 8];
#pragma unroll
            for (int i = 0; i < 4; i++)
#pragma unroll
                for (int j = 0; j < 2; j++)
                    acc[i * 2 + j] = __builtin_amdgcn_mfma_f32_16x16x32_bf16(af[i], bfr[j], acc[i * 2 + j], 0, 0, 0);
        } else {
#pragma unroll
            for (int i = 0; i < 2; i++) af[i]  = *(short8*)&wl[wr * 32 + i * 16 + li][quad * 8];
#pragma unroll
            for (int j = 0; j < 4; j++) bfr[j] = *(short8*)&xl[wc * 64 + j * 16 + li][quad * 8];
#pragma unroll
            for (int i = 0; i < 2; i++)
#pragma unroll
                for (int j = 0; j < 4; j++)
                    acc[i * 4 + j] = __builtin_amdgcn_mfma_f32_16x16x32_bf16(af[i], bfr[j], acc[i * 4 + j], 0, 0, 0);
        }
        __syncthreads();
    }

    if (which == 2) {          // V [b][c][n]
        short* outp = v + (size_t)b * C_ * N_;
#pragma unroll
        for (int i = 0; i < 2; i++) {
            int ob = o0 + wr * 32 + i * 16 + quad * 4;
#pragma unroll
            for (int j = 0; j < 4; j++) {
                int n_ = n0 + wc * 64 + j * 16 + li;
#pragma unroll
                for (int r = 0; r < 4; r++) {
                    float val = acc[i * 4 + j][r] + bias[ob + r];
                    outp[(size_t)(ob + r) * N_ + n_] = f2b(val);
                }
            }
        }
    } else if (which == 0) {   // Q^T [b][n][c], scaled
        short* outp = q + (size_t)b * N_ * C_;
#pragma unroll
        for (int i = 0; i < 4; i++) {
            int nb_ = n0 + wr * 64 + i * 16 + quad * 4;
#pragma unroll
            for (int j = 0; j < 2; j++) {
                int o_ = o0 + wc * 32 + j * 16 + li;
                float bv_ = bias[o_];
#pragma unroll
                for (int r = 0; r < 4; r++)
                    outp[(size_t)(nb_ + r) * C_ + o_] = f2b((acc[i * 2 + j][r] + bv_) * mul);
            }
        }
    } else {                   // K packed [b*8+h][m][32]
#pragma unroll
        for (int i = 0; i < 4; i++) {
            int nb_ = n0 + wr * 64 + i * 16 + quad * 4;
#pragma unroll
            for (int j = 0; j < 2; j++) {
                int o_ = o0 + wc * 32 + j * 16 + li;
                int hh = o_ >> 5, d = o_ & 31;
                float bv_ = bias[o_];
                short* kdst = kt + ((size_t)(b * 8 + hh) * N_) * HD_ + d;
#pragma unroll
                for (int r = 0; r < 4; r++)
                    kdst[(size_t)(nb_ + r) * HD_] = f2b(acc[i * 2 + j][r] + bv_);
            }
        }
    }
}

// ---------------- Node 3: flash v12 — 2-wave blocks, single-P pipelined, 4 blk/CU ----------
// Same lag-1 pipeline as v11, but P single-buffered (same-wave DS ordering makes the
// read(t-1)-before-write(t) sequence race-free) -> LDS 28.7KB -> grid 1024 at 4 blocks/CU.
#define STAGE_BARRIER(buf)                                                \
    *(short8*)&kl[(buf) * 2560 + klo] = kst0;                             \
    *(short8*)&kl[(buf) * 2560 + klo + 32 * 40] = kst1;                   \
    *(short8*)&vl[(buf) * 2304 + vlo] = vst0;                             \
    *(short8*)&vl[(buf) * 2304 + vlo + 16 * 72] = vst1;                   \
    __syncthreads();

#define PREFETCH(t1)                                                      \
    {                                                                     \
        int m1_ = (t1) * 64;                                              \
        kst0 = *(const short8*)(kgp + (size_t)m1_ * HD_);                 \
        kst1 = *(const short8*)(kgp + (size_t)(m1_ + 32) * HD_);          \
        vst0 = *(const short8*)(vgp + m1_);                               \
        vst1 = *(const short8*)(vgp + (size_t)16 * N_ + m1_);             \
    }

#define LOADVF(vf, bufv)                                                  \
    vf[0] = *(short8*)&vl[(bufv) * 2304 + li * 72 + quad * 8];            \
    vf[1] = *(short8*)&vl[(bufv) * 2304 + (16 + li) * 72 + quad * 8];     \
    vf[2] = *(short8*)&vl[(bufv) * 2304 + li * 72 + 32 + quad * 8];       \
    vf[3] = *(short8*)&vl[(bufv) * 2304 + (16 + li) * 72 + 32 + quad * 8];

#define QK(bufk)                                                          \
    _Pragma("unroll")                                                     \
    for (int c = 0; c < 4; c++) {                                         \
        short8 kf = *(short8*)&kl[(bufk) * 2560 + (c * 16 + li) * 40 + quad * 8]; \
        s0[c] = __builtin_amdgcn_mfma_f32_16x16x32_bf16(kf, qf0, zero, 0, 0, 0);  \
        s1[c] = __builtin_amdgcn_mfma_f32_16x16x32_bf16(kf, qf1, zero, 0, 0, 0);  \
    }

#define PV(vf)                                                            \
    {                                                                     \
        short8 pf00 = *(short8*)&pA[li * 72 + quad * 8];                  \
        short8 pf01 = *(short8*)&pA[li * 72 + 32 + quad * 8];             \
        short8 pf10 = *(short8*)&pA[1152 + li * 72 + quad * 8];           \
        short8 pf11 = *(short8*)&pA[1152 + li * 72 + 32 + quad * 8];      \
        oa00 = __builtin_amdgcn_mfma_f32_16x16x32_bf16(pf00, vf[0], oa00, 0, 0, 0); \
        oa01 = __builtin_amdgcn_mfma_f32_16x16x32_bf16(pf00, vf[1], oa01, 0, 0, 0); \
        oa00 = __builtin_amdgcn_mfma_f32_16x16x32_bf16(pf01, vf[2], oa00, 0, 0, 0); \
        oa01 = __builtin_amdgcn_mfma_f32_16x16x32_bf16(pf01, vf[3], oa01, 0, 0, 0); \
        oa10 = __builtin_amdgcn_mfma_f32_16x16x32_bf16(pf10, vf[0], oa10, 0, 0, 0); \
        oa11 = __builtin_amdgcn_mfma_f32_16x16x32_bf16(pf10, vf[1], oa11, 0, 0, 0); \
        oa10 = __builtin_amdgcn_mfma_f32_16x16x32_bf16(pf11, vf[2], oa10, 0, 0, 0); \
        oa11 = __builtin_amdgcn_mfma_f32_16x16x32_bf16(pf11, vf[3], oa11, 0, 0, 0); \
    }

#define EXPPACK()                                                         \
    {                                                                     \
        float lp = 0.f;                                                   \
        _Pragma("unroll")                                                 \
        for (int c = 0; c < 4; c++) {                                     \
            float e0 = __builtin_amdgcn_exp2f(s0[c][0]);                  \
            float e1 = __builtin_amdgcn_exp2f(s0[c][1]);                  \
            float e2 = __builtin_amdgcn_exp2f(s0[c][2]);                  \
            float e3 = __builtin_amdgcn_exp2f(s0[c][3]);                  \
            lp += (e0 + e1) + (e2 + e3);                                  \
            unsigned pk0 = __builtin_amdgcn_perm(__float_as_uint(e1), __float_as_uint(e0), 0x07060302); \
            unsigned pk1 = __builtin_amdgcn_perm(__float_as_uint(e3), __float_as_uint(e2), 0x07060302); \
            uint2 pkv; pkv.x = pk0; pkv.y = pk1;                          \
            *(uint2*)&pA[li * 72 + c * 16 + quad * 4] = pkv;              \
        }                                                                 \
        lr0 += lp;                                                        \
        lp = 0.f;                                                         \
        _Pragma("unroll")                                                 \
        for (int c = 0; c < 4; c++) {                                     \
            float e0 = __builtin_amdgcn_exp2f(s1[c][0]);                  \
            float e1 = __builtin_amdgcn_exp2f(s1[c][1]);                  \
            float e2 = __builtin_amdgcn_exp2f(s1[c][2]);                  \
            float e3 = __builtin_amdgcn_exp2f(s1[c][3]);                  \
            lp += (e0 + e1) + (e2 + e3);                                  \
            unsigned pk0 = __builtin_amdgcn_perm(__float_as_uint(e1), __float_as_uint(e0), 0x07060302); \
            unsigned pk1 = __builtin_amdgcn_perm(__float_as_uint(e3), __float_as_uint(e2), 0x07060302); \
            uint2 pkv; pkv.x = pk0; pkv.y = pk1;                          \
            *(uint2*)&pA[1152 + li * 72 + c * 16 + quad * 4] = pkv;       \
        }                                                                 \
        lr1 += lp;                                                        \
    }

__global__ __launch_bounds__(128) void flash(const short* __restrict__ q,
                                             const short* __restrict__ ktp,
                                             const short* __restrict__ v,
                                             short* __restrict__ aoT) {
    int bid = blockIdx.x;          // 0..1023
    int xcd = bid & 7;
    int s_  = bid >> 3;            // 0..127
    int bh  = xcd * 2 + (s_ & 1);
    int nb  = s_ >> 1;             // 0..63
    int b = bh >> 3, h = bh & 7;

    const short* QT = q   + (size_t)b * N_ * C_ + h * HD_;
    const short* KP = ktp + (size_t)bh * N_ * HD_;
    const short* V  = v   + ((size_t)b * C_ + h * HD_) * N_;
    short* O = aoT + (size_t)b * N_ * C_ + h * HD_;

    __shared__ short kl[2 * 2560];    // K tiles [m][40]
    __shared__ short vl[2 * 2304];    // V tiles [d][72]
    __shared__ short pl[2 * 2304];    // per-wave single P (2 groups x 1152)

    int tid = threadIdx.x, w = tid >> 6, lane = tid & 63, li = lane & 15, quad = lane >> 4;
    int n0w = nb * 64 + w * 32;
    short* pA = pl + w * 2304;

    short8 qf0 = *(const short8*)&QT[(size_t)(n0w + li) * 256 + quad * 8];
    short8 qf1 = *(const short8*)&QT[(size_t)(n0w + 16 + li) * 256 + quad * 8];

    f32x4 oa00 = (f32x4){0.f,0.f,0.f,0.f}, oa01 = oa00, oa10 = oa00, oa11 = oa00;
    float lr0 = 0.f, lr1 = 0.f;
    const f32x4 zero = (f32x4){0.f, 0.f, 0.f, 0.f};

    // staging: 128 threads x 2 passes cover 4KB K + 4KB V per tile
    int krow = tid >> 2, kcol = (tid & 3) << 3;     // K rows 0..31 (+32)
    int vrow = tid >> 3, vcol = (tid & 7) << 3;     // V d 0..15 (+16)
    const short* kgp = KP + (size_t)krow * HD_ + kcol;
    const short* vgp = V + (size_t)vrow * N_ + vcol;
    int klo = krow * 40 + kcol;
    int vlo = vrow * 72 + vcol;

    short8 kst0 = *(const short8*)kgp;
    short8 kst1 = *(const short8*)(kgp + (size_t)32 * HD_);
    short8 vst0 = *(const short8*)vgp;
    short8 vst1 = *(const short8*)(vgp + (size_t)16 * N_);
    short8 vfa[4], vfb[4];
    f32x4 s0[4], s1[4];

    // t = 0 (buf 0)
    STAGE_BARRIER(0);
    PREFETCH(1);
    QK(0);
    EXPPACK();
    LOADVF(vfa, 0);

    for (int mt = 1; mt < 62; mt += 2) {
        // t = mt (odd, buf 1)
        STAGE_BARRIER(1);
        PREFETCH(mt + 1);
        QK(1);
        PV(vfa);        // reads pA written at t-1 (in-order before EXPPACK's writes)
        EXPPACK();
        LOADVF(vfb, 1);
        // t = mt+1 (even, buf 0)
        STAGE_BARRIER(0);
        PREFETCH(mt + 2);
        QK(0);
        PV(vfb);
        EXPPACK();
        LOADVF(vfa, 0);
    }
    // t = 63 (odd, buf 1)
    STAGE_BARRIER(1);
    QK(1);
    PV(vfa);
    EXPPACK();
    LOADVF(vfb, 1);
    PV(vfb);            // final PV(63)

    lr0 += __shfl_xor(lr0, 16); lr0 += __shfl_xor(lr0, 32);
    lr1 += __shfl_xor(lr1, 16); lr1 += __shfl_xor(lr1, 32);
#pragma unroll
    for (int r2 = 0; r2 < 4; r2++) {
        float ln0 = __shfl(lr0, quad * 4 + r2);
        float inv0 = 1.f / ln0;
        size_t n_ = (size_t)(n0w + quad * 4 + r2);
        O[n_ * 256 + li]      = f2b(oa00[r2] * inv0);
        O[n_ * 256 + 16 + li] = f2b(oa01[r2] * inv0);
        float ln1 = __shfl(lr1, quad * 4 + r2);
        float inv1 = 1.f / ln1;
        size_t n2 = (size_t)(n0w + 16 + quad * 4 + r2);
        O[n2 * 256 + li]      = f2b(oa10[r2] * inv1);
        O[n2 * 256 + 16 + li] = f2b(oa11[r2] * inv1);
    }
}

// ---------------- Node 4: out projection (256 blocks, 1/CU) ----------------
__global__ __launch_bounds__(256) void gemm_out(const float* __restrict__ W,
                                                const float* __restrict__ bias,
                                                const short* __restrict__ aoT,
                                                const float* __restrict__ resid,
                                                float* __restrict__ out) {
    int b = blockIdx.z;
    const short* X = aoT + (size_t)b * N_ * C_;
    const float* R = resid + (size_t)b * C_ * N_;
    float* outp = out + (size_t)b * C_ * N_;

    __shared__ short wl[128][40];
    __shared__ short xl[64][40];

    int o0 = blockIdx.y * 128, n0 = blockIdx.x * 64;
    int tid = threadIdx.x;
    int w = tid >> 6, lane = tid & 63, li = lane & 15, quad = lane >> 4;
    int wr = w & 1, wc = w >> 1;

    f32x4 acc[4][2];
#pragma unroll
    for (int i = 0; i < 4; i++)
#pragma unroll
        for (int j = 0; j < 2; j++) acc[i][j] = (f32x4){0.f, 0.f, 0.f, 0.f};

    for (int k0 = 0; k0 < 256; k0 += 32) {
#pragma unroll
        for (int i = 0; i < 2; i++) {
            int idx = tid + i * 256;
            int row = idx >> 2, co = (idx & 3) << 3;
            const float* wp = &W[(size_t)(o0 + row) * 256 + k0 + co];
            f4 wa = *(const f4*)wp;
            f4 wb = *(const f4*)(wp + 4);
            short8 w8;
#pragma unroll
            for (int j = 0; j < 4; j++) { w8[j] = f2b(wa[j]); w8[j + 4] = f2b(wb[j]); }
            *(short8*)&wl[row][co] = w8;
        }
        {
            int row = tid >> 2, co = (tid & 3) << 3;
            *(short8*)&xl[row][co] = *(const short8*)&X[(size_t)(n0 + row) * 256 + k0 + co];
        }
        __syncthreads();
        short8 af[4], bfr[2];
#pragma unroll
        for (int i = 0; i < 4; i++) af[i]  = *(short8*)&wl[wr * 64 + i * 16 + li][quad * 8];
#pragma unroll
        for (int j = 0; j < 2; j++) bfr[j] = *(short8*)&xl[wc * 32 + j * 16 + li][quad * 8];
#pragma unroll
        for (int i = 0; i < 4; i++)
#pragma unroll
            for (int j = 0; j < 2; j++)
                acc[i][j] = __builtin_amdgcn_mfma_f32_16x16x32_bf16(af[i], bfr[j], acc[i][j], 0, 0, 0);
        __syncthreads();
    }
#pragma unroll
    for (int i = 0; i < 4; i++) {
        int ob = o0 + wr * 64 + i * 16 + quad * 4;
#pragma unroll
        for (int j = 0; j < 2; j++) {
            int n_ = n0 + wc * 32 + j * 16 + li;
#pragma unroll
            for (int r = 0; r < 4; r++) {
                size_t idx = (size_t)(ob + r) * N_ + n_;
                outp[idx] = acc[i][j][r] + bias[ob + r] + R[idx];
            }
        }
    }
}

extern "C" void kernel_launch(void* const* d_in, const int* in_sizes, int n_in,
                              void* d_out, int out_size, void* d_ws, size_t ws_size,
                              hipStream_t stream) {
    const float* x  = (const float*)d_in[0];
    const float* gw = (const float*)d_in[1];
    const float* gb = (const float*)d_in[2];
    const float* wq = (const float*)d_in[3];
    const float* bq = (const float*)d_in[4];
    const float* wk = (const float*)d_in[5];
    const float* bk = (const float*)d_in[6];
    const float* wv = (const float*)d_in[7];
    const float* bv = (const float*)d_in[8];
    const float* wo = (const float*)d_in[9];
    const float* bo = (const float*)d_in[10];
    float* out = (float*)d_out;

    char* ws = (char*)d_ws;
    float* part = (float*)ws;                  // 2048 floats
    const size_t TS = (size_t)B_ * N_ * C_;
    short* aoT = (short*)(ws + 16384);         // flash output [b][n][c]
    short* q   = aoT + TS;
    short* kt  = q + TS;                       // packed [b*8+h][m][32]
    short* v   = kt + TS;

    gn_part<<<1024, 256, 0, stream>>>(x, part);
    gemm_qkv<<<dim3(32, 4, 6), 256, 0, stream>>>(x, gw, gb, part,
                                                 wq, bq, wk, bk, wv, bv, q, kt, v);
    flash<<<1024, 128, 0, stream>>>(q, kt, v, aoT);
    gemm_out<<<dim3(64, 2, 2), 256, 0, stream>>>(wo, bo, aoT, x, out);
}

// Round 18
// 171.801 us; speedup vs baseline: 1.0205x; 1.0205x over previous
//
#include <hip/hip_runtime.h>

#define B_   2
#define C_   256
#define N_   4096
#define H_   8
#define HD_  32
#define G_   8
#define CPG_ 32

typedef short short8 __attribute__((ext_vector_type(8)));
typedef float f32x4  __attribute__((ext_vector_type(4)));
typedef float f4     __attribute__((ext_vector_type(4)));

__device__ __forceinline__ float b2f(short s) {
    return __uint_as_float(((unsigned)(unsigned short)s) << 16);
}
__device__ __forceinline__ short f2b(float f) {
    unsigned u = __float_as_uint(f);
    unsigned r = (u + 0x7FFF + ((u >> 16) & 1)) >> 16;  // RNE
    return (short)r;
}

// ---------------- Node 1: GN partial sums (1024 blocks) ----------------
__global__ __launch_bounds__(256) void gn_part(const float* __restrict__ x,
                                               float* __restrict__ part) {
    int blk = blockIdx.x;
    const f4* p = (const f4*)x + (size_t)(blk >> 6) * (CPG_ * N_ / 4) + (size_t)(blk & 63) * 512;
    float s = 0.f, ss = 0.f;
#pragma unroll
    for (int i = 0; i < 2; i++) {
        f4 v = p[threadIdx.x + i * 256];
#pragma unroll
        for (int j = 0; j < 4; j++) { float f = v[j]; s += f; ss += f * f; }
    }
#pragma unroll
    for (int off = 32; off > 0; off >>= 1) {
        s  += __shfl_down(s, off);
        ss += __shfl_down(ss, off);
    }
    __shared__ float rs[4], rss[4];
    int w = threadIdx.x >> 6;
    if ((threadIdx.x & 63) == 0) { rs[w] = s; rss[w] = ss; }
    __syncthreads();
    if (threadIdx.x == 0) {
        part[blk * 2]     = rs[0] + rs[1] + rs[2] + rs[3];
        part[blk * 2 + 1] = rss[0] + rss[1] + rss[2] + rss[3];
    }
}

// ---------------- Node 2: fused GN-apply + QKV GEMM (768 blocks, 3/CU) ----------------
// GN applied during LDS staging (no xnT round-trip). Channel-pair b32 LDS writes (2-way = free).
// which==0 -> Q^T [b][n][c] scaled; which==1 -> K packed [b*8+h][m][32]; which==2 -> V [b][c][n].
__global__ __launch_bounds__(256) void gemm_qkv(
    const float* __restrict__ x,
    const float* __restrict__ gw, const float* __restrict__ gb,
    const float* __restrict__ part,
    const float* __restrict__ wq, const float* __restrict__ bq,
    const float* __restrict__ wk, const float* __restrict__ bk,
    const float* __restrict__ wv, const float* __restrict__ bv,
    short* __restrict__ q, short* __restrict__ kt, short* __restrict__ v) {
    int z = blockIdx.z;
    int b = z / 3, which = z % 3;
    const float* W    = which == 0 ? wq : (which == 1 ? wk : wv);
    const float* bias = which == 0 ? bq : (which == 1 ? bk : bv);
    bool trans = (which != 2);
    float mul = (which == 0) ? (0.17677669529663687f * 1.4426950408889634f) : 1.0f;

    __shared__ short wl[64][40];
    __shared__ short xl[128][40];
    __shared__ float ga[256], gbb[256];
    __shared__ float mus[8], rstds[8];

    int o0 = blockIdx.y * 64, n0 = blockIdx.x * 128;
    int tid = threadIdx.x;
    int w = tid >> 6, lane = tid & 63, li = lane & 15, quad = lane >> 4;
    int wr = w & 1, wc = w >> 1;

    // prologue: wave w reduces groups 2w, 2w+1 from part[]
#pragma unroll
    for (int gi = 0; gi < 2; gi++) {
        int g = w * 2 + gi;
        const float* pp = &part[(size_t)(b * 8 + g) * 128 + lane * 2];
        float s = pp[0], ss = pp[1];
#pragma unroll
        for (int off = 32; off > 0; off >>= 1) {
            s  += __shfl_down(s, off);
            ss += __shfl_down(ss, off);
        }
        if (lane == 0) {
            const float inv = 1.f / (float)(CPG_ * N_);
            float mu = s * inv;
            float var = ss * inv - mu * mu;
            mus[g] = mu;
            rstds[g] = rsqrtf(var + 1e-5f);
        }
    }
    __syncthreads();
    {
        int c = tid, g = c >> 5;
        float a = rstds[g] * gw[c];
        ga[c]  = a;
        gbb[c] = gb[c] - mus[g] * a;
    }

    f32x4 acc[8];
#pragma unroll
    for (int i = 0; i < 8; i++) acc[i] = (f32x4){0.f, 0.f, 0.f, 0.f};

    int cpair = tid >> 4, l16 = tid & 15;
    __syncthreads();

    for (int k0 = 0; k0 < 256; k0 += 32) {
        {   // W: 64 rows x 32k -> 1 short8/thread (f32->bf16)
            int row = tid >> 2, co = (tid & 3) << 3;
            const float* wp = &W[(size_t)(o0 + row) * 256 + k0 + co];
            f4 wa = *(const f4*)wp;
            f4 wb = *(const f4*)(wp + 4);
            short8 w8;
#pragma unroll
            for (int j = 0; j < 4; j++) { w8[j] = f2b(wa[j]); w8[j + 4] = f2b(wb[j]); }
            *(short8*)&wl[row][co] = w8;
        }
        {   // X: GN-on-the-fly transpose staging (b32 channel-pair writes, 2-way banks)
            int c0 = k0 + cpair * 2;
            float a0 = ga[c0],     b0c = gbb[c0];
            float a1 = ga[c0 + 1], b1c = gbb[c0 + 1];
            const float* xr0 = x + ((size_t)(b * 256 + c0)) * N_ + n0 + l16;
            const float* xr1 = xr0 + N_;
#pragma unroll
            for (int j = 0; j < 8; j++) {
                unsigned lo = (unsigned short)f2b(xr0[16 * j] * a0 + b0c);
                unsigned hi = (unsigned short)f2b(xr1[16 * j] * a1 + b1c);
                *(unsigned*)&xl[l16 + 16 * j][cpair * 2] = lo | (hi << 16);
            }
        }
        __syncthreads();
        short8 af[4], bfr[4];
        if (trans) {   // rows = n (128), cols = o (64): 4x2
#pragma unroll
            for (int i = 0; i < 4; i++) af[i]  = *(short8*)&xl[wr * 64 + i * 16 + li][quad * 8];
#pragma unroll
            for (int j = 0; j < 2; j++) bfr[j] = *(short8*)&wl[wc * 32 + j * 16 + li][quad * 8];
#pragma unroll
            for (int i = 0; i < 4; i++)
#pragma unroll
                for (int j = 0; j < 2; j++)
                    acc[i * 2 + j] = __builtin_amdgcn_mfma_f32_16x16x32_bf16(af[i], bfr[j], acc[i * 2 + j], 0, 0, 0);
        } else {       // rows = o (64), cols = n (128): 2x4
#pragma unroll
            for (int i = 0; i < 2; i++) af[i]  = *(short8*)&wl[wr * 32 + i * 16 + li][quad * 8];
#pragma unroll
            for (int j = 0; j < 4; j++) bfr[j] = *(short8*)&xl[wc * 64 + j * 16 + li][quad * 8];
#pragma unroll
            for (int i = 0; i < 2; i++)
#pragma unroll
                for (int j = 0; j < 4; j++)
                    acc[i * 4 + j] = __builtin_amdgcn_mfma_f32_16x16x32_bf16(af[i], bfr[j], acc[i * 4 + j], 0, 0, 0);
        }
        __syncthreads();
    }

    if (which == 2) {          // V [b][c][n]
        short* outp = v + (size_t)b * C_ * N_;
#pragma unroll
        for (int i = 0; i < 2; i++) {
            int ob = o0 + wr * 32 + i * 16 + quad * 4;
#pragma unroll
            for (int j = 0; j < 4; j++) {
                int n_ = n0 + wc * 64 + j * 16 + li;
#pragma unroll
                for (int r = 0; r < 4; r++) {
                    float val = acc[i * 4 + j][r] + bias[ob + r];
                    outp[(size_t)(ob + r) * N_ + n_] = f2b(val);
                }
            }
        }
    } else if (which == 0) {   // Q^T [b][n][c], scaled
        short* outp = q + (size_t)b * N_ * C_;
#pragma unroll
        for (int i = 0; i < 4; i++) {
            int nb_ = n0 + wr * 64 + i * 16 + quad * 4;
#pragma unroll
            for (int j = 0; j < 2; j++) {
                int o_ = o0 + wc * 32 + j * 16 + li;
                float bv_ = bias[o_];
#pragma unroll
                for (int r = 0; r < 4; r++)
                    outp[(size_t)(nb_ + r) * C_ + o_] = f2b((acc[i * 2 + j][r] + bv_) * mul);
            }
        }
    } else {                   // K packed [b*8+h][m][32]
#pragma unroll
        for (int i = 0; i < 4; i++) {
            int nb_ = n0 + wr * 64 + i * 16 + quad * 4;
#pragma unroll
            for (int j = 0; j < 2; j++) {
                int o_ = o0 + wc * 32 + j * 16 + li;
                int hh = o_ >> 5, d = o_ & 31;
                float bv_ = bias[o_];
                short* kdst = kt + ((size_t)(b * 8 + hh) * N_) * HD_ + d;
#pragma unroll
                for (int r = 0; r < 4; r++)
                    kdst[(size_t)(nb_ + r) * HD_] = f2b(acc[i * 2 + j][r] + bv_);
            }
        }
    }
}

// ---------------- Node 3: flash v11 (best measured: 76.4-77 us) ----------------
#define STAGE_BARRIER(bufk, bufv)                                         \
    *(short8*)&kl[(bufk) * 2560 + klo] = kst;                             \
    *(short8*)&vl[(bufv) * 2304 + vlo] = vst;                             \
    __syncthreads();

#define PREFETCH(t1)                                                      \
    kst = *(const short8*)(kgp + (size_t)(t1) * 64 * HD_);                \
    vst = *(const short8*)(vgp + (t1) * 64);

#define LOADVF(vf, bufv)                                                  \
    vf[0] = *(short8*)&vl[(bufv) * 2304 + li * 72 + quad * 8];            \
    vf[1] = *(short8*)&vl[(bufv) * 2304 + (16 + li) * 72 + quad * 8];     \
    vf[2] = *(short8*)&vl[(bufv) * 2304 + li * 72 + 32 + quad * 8];       \
    vf[3] = *(short8*)&vl[(bufv) * 2304 + (16 + li) * 72 + 32 + quad * 8];

#define QK(bufk)                                                          \
    _Pragma("unroll")                                                     \
    for (int c = 0; c < 4; c++) {                                         \
        short8 kf = *(short8*)&kl[(bufk) * 2560 + (c * 16 + li) * 40 + quad * 8]; \
        s0[c] = __builtin_amdgcn_mfma_f32_16x16x32_bf16(kf, qf0, zero, 0, 0, 0);  \
        s1[c] = __builtin_amdgcn_mfma_f32_16x16x32_bf16(kf, qf1, zero, 0, 0, 0);  \
    }

#define PV(pP, vf)                                                        \
    {                                                                     \
        short8 pf00 = *(short8*)&(pP)[li * 72 + quad * 8];                \
        short8 pf01 = *(short8*)&(pP)[li * 72 + 32 + quad * 8];           \
        short8 pf10 = *(short8*)&(pP)[1152 + li * 72 + quad * 8];         \
        short8 pf11 = *(short8*)&(pP)[1152 + li * 72 + 32 + quad * 8];    \
        oa00 = __builtin_amdgcn_mfma_f32_16x16x32_bf16(pf00, vf[0], oa00, 0, 0, 0); \
        oa01 = __builtin_amdgcn_mfma_f32_16x16x32_bf16(pf00, vf[1], oa01, 0, 0, 0); \
        oa00 = __builtin_amdgcn_mfma_f32_16x16x32_bf16(pf01, vf[2], oa00, 0, 0, 0); \
        oa01 = __builtin_amdgcn_mfma_f32_16x16x32_bf16(pf01, vf[3], oa01, 0, 0, 0); \
        oa10 = __builtin_amdgcn_mfma_f32_16x16x32_bf16(pf10, vf[0], oa10, 0, 0, 0); \
        oa11 = __builtin_amdgcn_mfma_f32_16x16x32_bf16(pf10, vf[1], oa11, 0, 0, 0); \
        oa10 = __builtin_amdgcn_mfma_f32_16x16x32_bf16(pf11, vf[2], oa10, 0, 0, 0); \
        oa11 = __builtin_amdgcn_mfma_f32_16x16x32_bf16(pf11, vf[3], oa11, 0, 0, 0); \
    }

#define EXPPACK(pC)                                                       \
    {                                                                     \
        float lp = 0.f;                                                   \
        _Pragma("unroll")                                                 \
        for (int c = 0; c < 4; c++) {                                     \
            float e0 = __builtin_amdgcn_exp2f(s0[c][0]);                  \
            float e1 = __builtin_amdgcn_exp2f(s0[c][1]);                  \
            float e2 = __builtin_amdgcn_exp2f(s0[c][2]);                  \
            float e3 = __builtin_amdgcn_exp2f(s0[c][3]);                  \
            lp += (e0 + e1) + (e2 + e3);                                  \
            unsigned pk0 = __builtin_amdgcn_perm(__float_as_uint(e1), __float_as_uint(e0), 0x07060302); \
            unsigned pk1 = __builtin_amdgcn_perm(__float_as_uint(e3), __float_as_uint(e2), 0x07060302); \
            uint2 pkv; pkv.x = pk0; pkv.y = pk1;                          \
            *(uint2*)&(pC)[li * 72 + c * 16 + quad * 4] = pkv;            \
        }                                                                 \
        lr0 += lp;                                                        \
        lp = 0.f;                                                         \
        _Pragma("unroll")                                                 \
        for (int c = 0; c < 4; c++) {                                     \
            float e0 = __builtin_amdgcn_exp2f(s1[c][0]);                  \
            float e1 = __builtin_amdgcn_exp2f(s1[c][1]);                  \
            float e2 = __builtin_amdgcn_exp2f(s1[c][2]);                  \
            float e3 = __builtin_amdgcn_exp2f(s1[c][3]);                  \
            lp += (e0 + e1) + (e2 + e3);                                  \
            unsigned pk0 = __builtin_amdgcn_perm(__float_as_uint(e1), __float_as_uint(e0), 0x07060302); \
            unsigned pk1 = __builtin_amdgcn_perm(__float_as_uint(e3), __float_as_uint(e2), 0x07060302); \
            uint2 pkv; pkv.x = pk0; pkv.y = pk1;                          \
            *(uint2*)&(pC)[1152 + li * 72 + c * 16 + quad * 4] = pkv;     \
        }                                                                 \
        lr1 += lp;                                                        \
    }

__global__ __launch_bounds__(256) void flash(const short* __restrict__ q,
                                             const short* __restrict__ ktp,
                                             const short* __restrict__ v,
                                             short* __restrict__ aoT) {
    int bid = blockIdx.x;          // 0..511
    int xcd = bid & 7;
    int s_  = bid >> 3;
    int bh  = xcd * 2 + (s_ & 1);
    int nb  = s_ >> 1;             // 0..31
    int b = bh >> 3, h = bh & 7;

    const short* QT = q   + (size_t)b * N_ * C_ + h * HD_;
    const short* KP = ktp + (size_t)bh * N_ * HD_;
    const short* V  = v   + ((size_t)b * C_ + h * HD_) * N_;
    short* O = aoT + (size_t)b * N_ * C_ + h * HD_;

    __shared__ short kl[2 * 2560];
    __shared__ short vl[2 * 2304];
    __shared__ short pl[4 * 4608];

    int tid = threadIdx.x, w = tid >> 6, lane = tid & 63, li = lane & 15, quad = lane >> 4;
    int n0w = nb * 128 + w * 32;
    short* pA = pl + w * 4608;
    short* pB = pA + 2304;

    short8 qf0 = *(const short8*)&QT[(size_t)(n0w + li) * 256 + quad * 8];
    short8 qf1 = *(const short8*)&QT[(size_t)(n0w + 16 + li) * 256 + quad * 8];

    f32x4 oa00 = (f32x4){0.f,0.f,0.f,0.f}, oa01 = oa00, oa10 = oa00, oa11 = oa00;
    float lr0 = 0.f, lr1 = 0.f;
    const f32x4 zero = (f32x4){0.f, 0.f, 0.f, 0.f};

    int krow = tid >> 2, kcol = (tid & 3) << 3;
    int vrow = tid >> 3, vcol = (tid & 7) << 3;
    const short* kgp = KP + (size_t)krow * HD_ + kcol;
    const short* vgp = V + (size_t)vrow * N_ + vcol;
    int klo = krow * 40 + kcol;
    int vlo = vrow * 72 + vcol;

    short8 kst = *(const short8*)kgp;
    short8 vst = *(const short8*)vgp;
    short8 vfa[4], vfb[4];
    f32x4 s0[4], s1[4];

    STAGE_BARRIER(0, 0);
    PREFETCH(1);
    LOADVF(vfa, 0);
    QK(0);
    EXPPACK(pA);

    for (int mt = 1; mt < 62; mt += 2) {
        STAGE_BARRIER(1, 1);
        PREFETCH(mt + 1);
        LOADVF(vfb, 1);
        QK(1);
        PV(pA, vfa);
        EXPPACK(pB);
        STAGE_BARRIER(0, 0);
        PREFETCH(mt + 2);
        LOADVF(vfa, 0);
        QK(0);
        PV(pB, vfb);
        EXPPACK(pA);
    }
    STAGE_BARRIER(1, 1);
    LOADVF(vfb, 1);
    QK(1);
    PV(pA, vfa);
    EXPPACK(pB);
    PV(pB, vfb);

    lr0 += __shfl_xor(lr0, 16); lr0 += __shfl_xor(lr0, 32);
    lr1 += __shfl_xor(lr1, 16); lr1 += __shfl_xor(lr1, 32);
#pragma unroll
    for (int r2 = 0; r2 < 4; r2++) {
        float ln0 = __shfl(lr0, quad * 4 + r2);
        float inv0 = 1.f / ln0;
        size_t n_ = (size_t)(n0w + quad * 4 + r2);
        O[n_ * 256 + li]      = f2b(oa00[r2] * inv0);
        O[n_ * 256 + 16 + li] = f2b(oa01[r2] * inv0);
        float ln1 = __shfl(lr1, quad * 4 + r2);
        float inv1 = 1.f / ln1;
        size_t n2 = (size_t)(n0w + 16 + quad * 4 + r2);
        O[n2 * 256 + li]      = f2b(oa10[r2] * inv1);
        O[n2 * 256 + 16 + li] = f2b(oa11[r2] * inv1);
    }
}

// ---------------- Node 4: out projection (256 blocks, 1/CU) ----------------
__global__ __launch_bounds__(256) void gemm_out(const float* __restrict__ W,
                                                const float* __restrict__ bias,
                                                const short* __restrict__ aoT,
                                                const float* __restrict__ resid,
                                                float* __restrict__ out) {
    int b = blockIdx.z;
    const short* X = aoT + (size_t)b * N_ * C_;
    const float* R = resid + (size_t)b * C_ * N_;
    float* outp = out + (size_t)b * C_ * N_;

    __shared__ short wl[128][40];
    __shared__ short xl[64][40];

    int o0 = blockIdx.y * 128, n0 = blockIdx.x * 64;
    int tid = threadIdx.x;
    int w = tid >> 6, lane = tid & 63, li = lane & 15, quad = lane >> 4;
    int wr = w & 1, wc = w >> 1;

    f32x4 acc[4][2];
#pragma unroll
    for (int i = 0; i < 4; i++)
#pragma unroll
        for (int j = 0; j < 2; j++) acc[i][j] = (f32x4){0.f, 0.f, 0.f, 0.f};

    for (int k0 = 0; k0 < 256; k0 += 32) {
#pragma unroll
        for (int i = 0; i < 2; i++) {
            int idx = tid + i * 256;
            int row = idx >> 2, co = (idx & 3) << 3;
            const float* wp = &W[(size_t)(o0 + row) * 256 + k0 + co];
            f4 wa = *(const f4*)wp;
            f4 wb = *(const f4*)(wp + 4);
            short8 w8;
#pragma unroll
            for (int j = 0; j < 4; j++) { w8[j] = f2b(wa[j]); w8[j + 4] = f2b(wb[j]); }
            *(short8*)&wl[row][co] = w8;
        }
        {
            int row = tid >> 2, co = (tid & 3) << 3;
            *(short8*)&xl[row][co] = *(const short8*)&X[(size_t)(n0 + row) * 256 + k0 + co];
        }
        __syncthreads();
        short8 af[4], bfr[2];
#pragma unroll
        for (int i = 0; i < 4; i++) af[i]  = *(short8*)&wl[wr * 64 + i * 16 + li][quad * 8];
#pragma unroll
        for (int j = 0; j < 2; j++) bfr[j] = *(short8*)&xl[wc * 32 + j * 16 + li][quad * 8];
#pragma unroll
        for (int i = 0; i < 4; i++)
#pragma unroll
            for (int j = 0; j < 2; j++)
                acc[i][j] = __builtin_amdgcn_mfma_f32_16x16x32_bf16(af[i], bfr[j], acc[i][j], 0, 0, 0);
        __syncthreads();
    }
#pragma unroll
    for (int i = 0; i < 4; i++) {
        int ob = o0 + wr * 64 + i * 16 + quad * 4;
#pragma unroll
        for (int j = 0; j < 2; j++) {
            int n_ = n0 + wc * 32 + j * 16 + li;
#pragma unroll
            for (int r = 0; r < 4; r++) {
                size_t idx = (size_t)(ob + r) * N_ + n_;
                outp[idx] = acc[i][j][r] + bias[ob + r] + R[idx];
            }
        }
    }
}

extern "C" void kernel_launch(void* const* d_in, const int* in_sizes, int n_in,
                              void* d_out, int out_size, void* d_ws, size_t ws_size,
                              hipStream_t stream) {
    const float* x  = (const float*)d_in[0];
    const float* gw = (const float*)d_in[1];
    const float* gb = (const float*)d_in[2];
    const float* wq = (const float*)d_in[3];
    const float* bq = (const float*)d_in[4];
    const float* wk = (const float*)d_in[5];
    const float* bk = (const float*)d_in[6];
    const float* wv = (const float*)d_in[7];
    const float* bv = (const float*)d_in[8];
    const float* wo = (const float*)d_in[9];
    const float* bo = (const float*)d_in[10];
    float* out = (float*)d_out;

    char* ws = (char*)d_ws;
    float* part = (float*)ws;                  // 2048 floats
    const size_t TS = (size_t)B_ * N_ * C_;
    short* aoT = (short*)(ws + 16384);         // flash output [b][n][c]
    short* q   = aoT + TS;
    short* kt  = q + TS;                       // packed [b*8+h][m][32]
    short* v   = kt + TS;

    gn_part<<<1024, 256, 0, stream>>>(x, part);
    gemm_qkv<<<dim3(32, 4, 6), 256, 0, stream>>>(x, gw, gb, part,
                                                 wq, bq, wk, bk, wv, bv, q, kt, v);
    flash<<<512, 256, 0, stream>>>(q, kt, v, aoT);
    gemm_out<<<dim3(64, 2, 2), 256, 0, stream>>>(wo, bo, aoT, x, out);
}